// Round 15
// baseline (1239.752 us; speedup 1.0000x reference)
//
#include <hip/hip_runtime.h>
#include <hip/hip_bf16.h>
#include <math.h>

// Problem constants
#define NFE 17      // graph nodes (features)
#define T2V 16      // time2vec dim
#define D0C 34      // 2 + 2*T2V
#define BB 128      // batch
#define TT 256      // seq len
#define HH 128      // GRU hidden
#define ASTR 136    // bf16 split-buffer row stride; 136*2B=272B -> 16B aligned
#define KSTR 40     // P^T k-stride: 80B rows, 16B aligned
#define ESTR 40     // E row stride; 80B rows, 16B aligned
#define EHSTR 680   // E head stride = 17*ESTR

typedef __hip_bfloat16 bf16;
__device__ __forceinline__ float b2f(bf16 x) { return __bfloat162float(x); }

// MFMA fragment types (gfx950 16x16x32 bf16: 8 bf16 in / 4 f32 acc per lane)
typedef __attribute__((ext_vector_type(8))) __bf16 bfrag;
typedef __attribute__((ext_vector_type(4))) float  ffrag;
typedef __attribute__((ext_vector_type(4))) __bf16 bf4;

// fast transcendentals (native v_exp_f32/v_sin_f32; ~2ulp)
__device__ __forceinline__ float elu_fast(float v)  { return v > 0.f ? v : __expf(v) - 1.f; }
__device__ __forceinline__ float sigm_fast(float x) { return __fdividef(1.f, 1.f + __expf(-x)); }
__device__ __forceinline__ float tanh_fast(float x) {
  return __fdividef(2.f, 1.f + __expf(-2.f*x)) - 1.f;
}

// ---------------- GAT weight fragment tables (prep once per launch) ----------
// R26: tables now carry 9 n-tiles. Tiles 0..7 = W columns (as before).
// Tile 8 = SCORE columns: col c<4 -> va_src[h=c] = W[:,h-slice]@asrc_h,
// c in 4..7 -> va_dst[h=c-4], c>=8 -> 0. Then es = A@va_src, ed = A@va_dst
// come out of the projection MFMA (math: es[h][f] = P[f,h-slice].a_h =
// A[f,:].(W@a)) — the f32 s_p buffer and the scores dot+shfl phase die.
//   index = ((nt*KSTEPS + ks)*64 + lane)*8 + j
//   n = nt*16 + (lane&15), k = ks*32 + (lane>>4)*8 + j
__device__ __bf16 g_W0h[9216],  g_W0l[9216];    // KSTEPS=2 (K 34 -> pad 64)
__device__ __bf16 g_W1h[18432], g_W1l[18432];   // KSTEPS=4 (K=128)

__global__ __launch_bounds__(256) void prep_w(
    const float* __restrict__ W0, const float* __restrict__ W1,
    const float* __restrict__ as0, const float* __restrict__ ad0,
    const float* __restrict__ as1, const float* __restrict__ ad1) {
  const int tid = blockIdx.x*256 + threadIdx.x;
  if (tid < 18432) {   // W1 table, 9 tiles
    const int j = tid & 7, lane = (tid >> 3) & 63, ks = (tid >> 9) & 3, nt = tid >> 11;
    const int c = lane & 15, k = ks*32 + (lane >> 4)*8 + j;
    float v = 0.f;
    if (nt < 8) {
      v = W1[k*128 + nt*16 + c];
    } else if (c < 8) {
      const int h = c & 3;
      const float* av = (c < 4) ? as1 : ad1;
      #pragma unroll
      for (int o = 0; o < 32; ++o)
        v = fmaf(W1[k*128 + h*32 + o], av[h*32 + o], v);
    }
    const __bf16 hi = (__bf16)v;
    g_W1h[tid] = hi;
    g_W1l[tid] = (__bf16)(v - (float)hi);
  }
  if (tid < 9216) {    // W0 table, 9 tiles (k>=D0C rows are zero)
    const int j = tid & 7, lane = (tid >> 3) & 63, ks = (tid >> 9) & 1, nt = tid >> 10;
    const int c = lane & 15, k = ks*32 + (lane >> 4)*8 + j;
    float v = 0.f;
    if (k < D0C) {
      if (nt < 8) {
        v = W0[k*128 + nt*16 + c];
      } else if (c < 8) {
        const int h = c & 3;
        const float* av = (c < 4) ? as0 : ad0;
        #pragma unroll
        for (int o = 0; o < 32; ++o)
          v = fmaf(W0[k*128 + h*32 + o], av[h*32 + o], v);
      }
    }
    const __bf16 hi = (__bf16)v;
    g_W0h[tid] = hi;
    g_W0l[tid] = (__bf16)(v - (float)hi);
  }
}

// ---------------- GAT building blocks ----------------------------------------
// Proj: wave wv does n-tiles {2wv, 2wv+1}; wave 0 ALSO does score-tile 8
// (wave-uniform branch; +6*KSTEPS MFMAs on a 16%-utilized pipe).
template<int KSTEPS>
__device__ __forceinline__ void gat_proj_mfma(const __bf16* s_ah, const __bf16* s_al,
                                              const __bf16* __restrict__ Wth,
                                              const __bf16* __restrict__ Wtl,
                                              __bf16* s_pth, __bf16* s_ptl,
                                              float* s_es, float* s_ed, int tid)
{
  const int lane = tid & 63, wv = tid >> 6;
  const int mn = lane & 15, q = lane >> 4;
  ffrag acc[2][2] = {};
  ffrag acc2[2] = {};                 // score tile (wave 0 only)
  #pragma unroll
  for (int ks = 0; ks < KSTEPS; ++ks) {
    const bfrag ah0 = *(const bfrag*)&s_ah[(     mn)*ASTR + ks*32 + q*8];
    const bfrag al0 = *(const bfrag*)&s_al[(     mn)*ASTR + ks*32 + q*8];
    const bfrag ah1 = *(const bfrag*)&s_ah[(16 + mn)*ASTR + ks*32 + q*8]; // rows 17+ garbage, discarded
    const bfrag al1 = *(const bfrag*)&s_al[(16 + mn)*ASTR + ks*32 + q*8];
    #pragma unroll
    for (int nt = 0; nt < 2; ++nt) {
      const int fi = (((wv*2 + nt)*KSTEPS + ks)*64 + lane)*8;
      const bfrag bh = *(const bfrag*)&Wth[fi];
      const bfrag bl = *(const bfrag*)&Wtl[fi];
      acc[0][nt] = __builtin_amdgcn_mfma_f32_16x16x32_bf16(al0, bh, acc[0][nt], 0,0,0);
      acc[0][nt] = __builtin_amdgcn_mfma_f32_16x16x32_bf16(ah0, bl, acc[0][nt], 0,0,0);
      acc[0][nt] = __builtin_amdgcn_mfma_f32_16x16x32_bf16(ah0, bh, acc[0][nt], 0,0,0);
      acc[1][nt] = __builtin_amdgcn_mfma_f32_16x16x32_bf16(al1, bh, acc[1][nt], 0,0,0);
      acc[1][nt] = __builtin_amdgcn_mfma_f32_16x16x32_bf16(ah1, bl, acc[1][nt], 0,0,0);
      acc[1][nt] = __builtin_amdgcn_mfma_f32_16x16x32_bf16(ah1, bh, acc[1][nt], 0,0,0);
    }
    if (wv == 0) {                    // score tile nt=8
      const int fi = ((8*KSTEPS + ks)*64 + lane)*8;
      const bfrag bh = *(const bfrag*)&Wth[fi];
      const bfrag bl = *(const bfrag*)&Wtl[fi];
      acc2[0] = __builtin_amdgcn_mfma_f32_16x16x32_bf16(al0, bh, acc2[0], 0,0,0);
      acc2[0] = __builtin_amdgcn_mfma_f32_16x16x32_bf16(ah0, bl, acc2[0], 0,0,0);
      acc2[0] = __builtin_amdgcn_mfma_f32_16x16x32_bf16(ah0, bh, acc2[0], 0,0,0);
      acc2[1] = __builtin_amdgcn_mfma_f32_16x16x32_bf16(al1, bh, acc2[1], 0,0,0);
      acc2[1] = __builtin_amdgcn_mfma_f32_16x16x32_bf16(ah1, bl, acc2[1], 0,0,0);
      acc2[1] = __builtin_amdgcn_mfma_f32_16x16x32_bf16(ah1, bh, acc2[1], 0,0,0);
    }
  }
  // C/D: col = lane&15 (+16*nt +32*wv), row = q*4+i (tile0) / 16 (tile1,q0).
  // Split-bf16 P^T [n][KSTR] only (f32 s_p deleted — scores come from MFMA).
  const int n0 = wv*32;
  #pragma unroll
  for (int nt = 0; nt < 2; ++nt) {
    const int col = n0 + nt*16 + mn;
    __bf16 hbuf[4], lbuf[4];
    #pragma unroll
    for (int i = 0; i < 4; ++i) {
      const float v = acc[0][nt][i];
      const __bf16 hi = (__bf16)v;
      hbuf[i] = hi;
      lbuf[i] = (__bf16)(v - (float)hi);
    }
    *(bf4*)&s_pth[col*KSTR + q*4] = *(bf4*)hbuf;
    *(bf4*)&s_ptl[col*KSTR + q*4] = *(bf4*)lbuf;
    if (q == 0) {
      const float v = acc[1][nt][0];
      const __bf16 hi = (__bf16)v;
      s_pth[col*KSTR + 16] = hi;
      s_ptl[col*KSTR + 16] = (__bf16)(v - (float)hi);
    }
  }
  if (wv == 0 && mn < 8) {            // score epilogue: col c=mn -> es/ed
    const int h = mn & 3;
    float* dst = (mn >= 4) ? s_ed : s_es;
    #pragma unroll
    for (int i = 0; i < 4; ++i)
      dst[h*NFE + q*4 + i] = acc2[0][i];
    if (q == 0) dst[h*NFE + 16] = acc2[1][0];
  }
}

// softmax + E-write, one wave per head; es/ed read from LDS (broadcast).
__device__ __forceinline__ void gat_softmax(const float* s_es, const float* s_ed,
                                            const float* s_adj,
                                            __bf16* s_Eh, __bf16* s_El, int tid) {
  const int lane = tid & 63, h = tid >> 6;   // wave h = head h
  if (lane < NFE) {
    const int i = lane;
    const float esv = s_es[h*NFE + i];
    float row[NFE]; float mx = -1e30f;
    #pragma unroll
    for (int j = 0; j < NFE; ++j) {
      float v = -1.0e9f;
      if (s_adj[i*NFE + j] > 0.f) {
        const float e = esv + s_ed[h*NFE + j];
        v = (e > 0.f) ? e : 0.2f*e;    // leaky_relu 0.2
      }
      row[j] = v; mx = fmaxf(mx, v);
    }
    float sum = 0.f;
    #pragma unroll
    for (int j = 0; j < NFE; ++j) { row[j] = __expf(row[j] - mx); sum += row[j]; }
    const float inv = __fdividef(1.f, sum);
    __bf16 hrow[32], lrow[32];
    #pragma unroll
    for (int j = 0; j < 32; ++j) {
      const float v = (j < NFE) ? row[j]*inv : 0.f;
      const __bf16 hi = (__bf16)v;
      hrow[j] = hi;
      lrow[j] = (__bf16)(v - (float)hi);
    }
    #pragma unroll
    for (int w = 0; w < 4; ++w) {
      *(bfrag*)&s_Eh[h*EHSTR + i*ESTR + w*8] = *(bfrag*)&hrow[w*8];
      *(bfrag*)&s_El[h*EHSTR + i*ESTR + w*8] = *(bfrag*)&lrow[w*8];
    }
  }
}

// out-stage core: b128-load E fragments and do O = E.P per head
__device__ __forceinline__ void gat_out_core(const __bf16* s_Eh, const __bf16* s_El,
                                             const __bf16* s_pth, const __bf16* s_ptl,
                                             int wv, int mn, int q, ffrag acc[2][2]) {
  const bfrag eh0 = *(const bfrag*)&s_Eh[wv*EHSTR + mn*ESTR + q*8];
  const bfrag el0 = *(const bfrag*)&s_El[wv*EHSTR + mn*ESTR + q*8];
  const bfrag eh1 = *(const bfrag*)&s_Eh[wv*EHSTR + (16+mn)*ESTR + q*8]; // rows 17+ garbage, discarded
  const bfrag el1 = *(const bfrag*)&s_El[wv*EHSTR + (16+mn)*ESTR + q*8];
  #pragma unroll
  for (int nt = 0; nt < 2; ++nt) {
    const int nrow = wv*32 + nt*16 + mn;
    const bfrag ph = *(const bfrag*)&s_pth[nrow*KSTR + q*8];
    const bfrag pl = *(const bfrag*)&s_ptl[nrow*KSTR + q*8];
    acc[0][nt] = __builtin_amdgcn_mfma_f32_16x16x32_bf16(el0, ph, acc[0][nt], 0,0,0);
    acc[0][nt] = __builtin_amdgcn_mfma_f32_16x16x32_bf16(eh0, pl, acc[0][nt], 0,0,0);
    acc[0][nt] = __builtin_amdgcn_mfma_f32_16x16x32_bf16(eh0, ph, acc[0][nt], 0,0,0);
    acc[1][nt] = __builtin_amdgcn_mfma_f32_16x16x32_bf16(el1, ph, acc[1][nt], 0,0,0);
    acc[1][nt] = __builtin_amdgcn_mfma_f32_16x16x32_bf16(eh1, pl, acc[1][nt], 0,0,0);
    acc[1][nt] = __builtin_amdgcn_mfma_f32_16x16x32_bf16(eh1, ph, acc[1][nt], 0,0,0);
  }
}

// layer-0 out: h = elu(E.P) -> split bf16 into s_ah/s_al (proj1 input)
__device__ __forceinline__ void gat_out0(const __bf16* s_Eh, const __bf16* s_El,
                                         const __bf16* s_pth, const __bf16* s_ptl,
                                         __bf16* s_ah, __bf16* s_al, int tid) {
  const int lane = tid & 63, wv = tid >> 6;   // wv = head
  const int mn = lane & 15, q = lane >> 4;
  ffrag acc[2][2] = {};
  gat_out_core(s_Eh, s_El, s_pth, s_ptl, wv, mn, q, acc);
  #pragma unroll
  for (int nt = 0; nt < 2; ++nt) {
    const int c = wv*32 + nt*16 + mn;
    #pragma unroll
    for (int i = 0; i < 4; ++i) {
      const float v = elu_fast(acc[0][nt][i]);
      const __bf16 hi = (__bf16)v;
      s_ah[(q*4+i)*ASTR + c] = hi;
      s_al[(q*4+i)*ASTR + c] = (__bf16)(v - (float)hi);
    }
    if (q == 0) {
      const float v = elu_fast(acc[1][nt][0]);
      const __bf16 hi = (__bf16)v;
      s_ah[16*ASTR + c] = hi;
      s_al[16*ASTR + c] = (__bf16)(v - (float)hi);
    }
  }
}

// layer-1 out: + residual + elu + column-mean (shfl-reduce) -> global z
__device__ __forceinline__ void gat_out1(const __bf16* s_Eh, const __bf16* s_El,
                                         const __bf16* s_pth, const __bf16* s_ptl,
                                         const __bf16* s_ah, const __bf16* s_al,
                                         float* __restrict__ zrow, int tid) {
  const int lane = tid & 63, wv = tid >> 6;   // wv = head
  const int mn = lane & 15, q = lane >> 4;
  ffrag acc[2][2] = {};
  gat_out_core(s_Eh, s_El, s_pth, s_ptl, wv, mn, q, acc);
  #pragma unroll
  for (int nt = 0; nt < 2; ++nt) {
    const int c = wv*32 + nt*16 + mn;
    float sum = 0.f;
    #pragma unroll
    for (int i = 0; i < 4; ++i) {
      const int r = q*4 + i;
      const float res = (float)s_ah[r*ASTR + c] + (float)s_al[r*ASTR + c];
      sum += elu_fast(acc[0][nt][i] + res);
    }
    sum += __shfl_xor(sum, 16);
    sum += __shfl_xor(sum, 32);
    if (q == 0) {
      const float res = (float)s_ah[16*ASTR + c] + (float)s_al[16*ASTR + c];
      sum += elu_fast(acc[1][nt][0] + res);
      zrow[c] = sum * (1.0f/17.0f);
    }
  }
}

// --------------- fused featurize + GAT0 + GAT1 + node-mean -------------------
// Flat LDS carve (byte offsets; all 16B aligned):
//  s_ah   @0      4624   } tile-1 frag reads intentionally run past into
//  s_al   @4624   4624   } following regions (finite/discarded-rows only)
//  s_Eh   @9248   5440   ([4][17][ESTR=40] bf16; j-pads zero)
//  s_El   @14688  5440
//  s_pth  @20128  10240  (P^T split hi, [n=128][KSTR=40]; k 17..39 stay 0)
//  s_ptl  @30368  10240
//  s_es   @40608  272    (MFMA-produced scores)
//  s_ed   @40880  272
//  s_t    @41152  64
//  s_adj  @41216  1156
//  total  42372 -> 42496 => 3 blocks/CU
__global__ __launch_bounds__(256) void gat_fused(
    const float* __restrict__ X,  const float* __restrict__ Mk,
    const float* __restrict__ Dl, const float* __restrict__ Tm,
    const float* __restrict__ Adj,
    const float* __restrict__ aw0, const float* __restrict__ ab0,
    const float* __restrict__ aW,  const float* __restrict__ aB,
    const float* __restrict__ dw0, const float* __restrict__ db0,
    const float* __restrict__ dW,  const float* __restrict__ dB,
    float* __restrict__ zslot)         // [B*T][256], z goes in cols 128..255
{
  __shared__ __align__(16) unsigned char smem[42372];
  __bf16* s_ah  = (__bf16*)(smem);
  __bf16* s_al  = (__bf16*)(smem + 4624);
  __bf16* s_Eh  = (__bf16*)(smem + 9248);
  __bf16* s_El  = (__bf16*)(smem + 14688);
  __bf16* s_pth = (__bf16*)(smem + 20128);
  __bf16* s_ptl = (__bf16*)(smem + 30368);
  float*  s_es  = (float*)(smem + 40608);
  float*  s_ed  = (float*)(smem + 40880);
  float*  s_t   = (float*)(smem + 41152);
  float*  s_adj = (float*)(smem + 41216);
  const int n = blockIdx.x;            // n = b*T + t  (matches times layout)
  const int tid = threadIdx.x;

  // zero P^T split buffers once: k-pad 17..39 MUST be 0 (proj only ever
  // writes k 0..16, so the pad stays 0 across both layers).
  // Region [20128, 40608) = 20480 B = 1280 float4.
  {
    const float4 z4 = {0.f, 0.f, 0.f, 0.f};
    float4* zp = (float4*)(smem + 20128);
    for (int i = tid; i < 1280; i += 256) zp[i] = z4;
  }
  const float tv = Tm[n];
  if (tid < T2V) {
    s_t[tid] = (tid == 0) ? fmaf(tv, aw0[0], ab0[0])
                          : __sinf(fmaf(tv, aW[tid-1], aB[tid-1]));
  }
  for (int idx = tid; idx < NFE*NFE; idx += 256) s_adj[idx] = Adj[idx];
  __syncthreads();
  // node features: [X, mask, t_emb(16), d_emb(16), 0-pad to 64] -> split bf16.
  // K-pad cols of real rows MUST be zero (NaN*0=NaN would hit real rows).
  for (int idx = tid; idx < NFE*64; idx += 256) {
    const int f = idx >> 6, c = idx & 63;
    float v = 0.f;
    if (c == 0)            v = X [(size_t)n*NFE + f];
    else if (c == 1)       v = Mk[(size_t)n*NFE + f];
    else if (c < 2 + T2V)  v = s_t[c-2];
    else if (c < D0C) {
      const float dd = Dl[(size_t)n*NFE + f];
      const int j = c - (2 + T2V);
      v = (j == 0) ? fmaf(dd, dw0[0], db0[0])
                   : __sinf(fmaf(dd, dW[j-1], dB[j-1]));
    }
    const __bf16 hi = (__bf16)v;
    s_ah[f*ASTR + c] = hi;
    s_al[f*ASTR + c] = (__bf16)(v - (float)hi);
  }
  __syncthreads();
  // GAT layer 0 (no residual)
  gat_proj_mfma<2>(s_ah, s_al, g_W0h, g_W0l, s_pth, s_ptl, s_es, s_ed, tid);
  __syncthreads();
  gat_softmax(s_es, s_ed, s_adj, s_Eh, s_El, tid);
  __syncthreads();
  gat_out0(s_Eh, s_El, s_pth, s_ptl, s_ah, s_al, tid);
  __syncthreads();
  // GAT layer 1 (residual) -> out + fused node-mean -> global
  gat_proj_mfma<4>(s_ah, s_al, g_W1h, g_W1l, s_pth, s_ptl, s_es, s_ed, tid);
  __syncthreads();
  gat_softmax(s_es, s_ed, s_adj, s_Eh, s_El, tid);
  __syncthreads();
  gat_out1(s_Eh, s_El, s_pth, s_ptl, s_ah, s_al,
           zslot + (size_t)n*256 + 128, tid);
}

// ------- MFMA GEMM (full split-precision): C = A(f32)*W(f32)^T + bias
// A = Ahi+Alo, W = Whi+Wlo (bf16 pairs). C ≈ Alo*Whi + Ahi*Wlo + Ahi*Whi
// (Alo*Wlo ~2^-18 dropped) -> ~fp32 accuracy.
// fwd/bwd directions merged into one dispatch via blockIdx.z (R10-proven).
// W staged in LDS (shared by all 4 waves) — R13's per-wave table variant
// measured neutral-to-worse.
__global__ __launch_bounds__(256) void gemm_xw_mfma(
    const float* __restrict__ A, int lda,
    const float* __restrict__ Wf, const float* __restrict__ biasf,
    bf16* __restrict__ Cf,
    const float* __restrict__ Wb, const float* __restrict__ biasb,
    bf16* __restrict__ Cb, int K)
{
  const float* W    = blockIdx.z ? Wb : Wf;
  const float* bias = blockIdx.z ? biasb : biasf;
  bf16*        C    = blockIdx.z ? Cb : Cf;
  __shared__ __bf16 Ah[64][40];   // pad 32->40: row = 80 B (16B-aligned)
  __shared__ __bf16 Al[64][40];
  __shared__ __bf16 Wh[64][40];
  __shared__ __bf16 Wl[64][40];
  const int tid = threadIdx.x;
  const int bm0 = blockIdx.x * 64;
  const int bn0 = blockIdx.y * 64;
  const int lane = tid & 63, wv = tid >> 6;
  const int mn = lane & 15, q = lane >> 4;
  const int sr = tid >> 2, sk = (tid & 3) * 8;   // staging: row, k-offset
  ffrag acc[4] = {};
  for (int kk = 0; kk < K; kk += 32) {
    // stage A and W chunks, each split hi/lo; coalesced float4 reads
    {
      float av[8];
      *(float4*)&av[0] = *(const float4*)&A[(size_t)(bm0 + sr)*lda + kk + sk];
      *(float4*)&av[4] = *(const float4*)&A[(size_t)(bm0 + sr)*lda + kk + sk + 4];
      __bf16 th[8], tl[8];
      #pragma unroll
      for (int i = 0; i < 8; ++i) {
        const __bf16 hi = (__bf16)av[i];
        th[i] = hi;
        tl[i] = (__bf16)(av[i] - (float)hi);
      }
      *(bfrag*)&Ah[sr][sk] = *(bfrag*)th;
      *(bfrag*)&Al[sr][sk] = *(bfrag*)tl;
      float wv8[8];
      *(float4*)&wv8[0] = *(const float4*)&W[(size_t)(bn0 + sr)*K + kk + sk];
      *(float4*)&wv8[4] = *(const float4*)&W[(size_t)(bn0 + sr)*K + kk + sk + 4];
      __bf16 wh8[8], wl8[8];
      #pragma unroll
      for (int i = 0; i < 8; ++i) {
        const __bf16 hi = (__bf16)wv8[i];
        wh8[i] = hi;
        wl8[i] = (__bf16)(wv8[i] - (float)hi);
      }
      *(bfrag*)&Wh[sr][sk] = *(bfrag*)wh8;
      *(bfrag*)&Wl[sr][sk] = *(bfrag*)wl8;
    }
    __syncthreads();
    const bfrag afh = *(const bfrag*)&Ah[16*wv + mn][q*8];
    const bfrag afl = *(const bfrag*)&Al[16*wv + mn][q*8];
    #pragma unroll
    for (int t = 0; t < 4; ++t) {
      const bfrag bwh = *(const bfrag*)&Wh[16*t + mn][q*8];
      const bfrag bwl = *(const bfrag*)&Wl[16*t + mn][q*8];
      acc[t] = __builtin_amdgcn_mfma_f32_16x16x32_bf16(afl, bwh, acc[t], 0, 0, 0);
      acc[t] = __builtin_amdgcn_mfma_f32_16x16x32_bf16(afh, bwl, acc[t], 0, 0, 0);
      acc[t] = __builtin_amdgcn_mfma_f32_16x16x32_bf16(afh, bwh, acc[t], 0, 0, 0);
    }
    __syncthreads();
  }
  // epilogue: C[m][n] = acc + bias
  #pragma unroll
  for (int t = 0; t < 4; ++t) {
    const int col = bn0 + 16*t + mn;
    const float bv = bias[col];
    #pragma unroll
    for (int i = 0; i < 4; ++i) {
      const int row = bm0 + 16*wv + q*4 + i;
      C[(size_t)row*384 + col] = __float2bfloat16(acc[t][i] + bv);
    }
  }
}

// ---------------- GRU recurrence: one block per (dir, batch-row) -------------
// R23-proven: dependent-chain split. Thread (g,p) computes the half-dot over
// d in [p*64, p*64+64) (64-deep chain vs 128; w-regs halve -> no spill).
// p=1 stores its partial; gate threads add it — no extra barrier.
__global__ __launch_bounds__(768, 1) void gru_rec(
    const bf16* __restrict__ gxf,      // [B][T][384] forward-dir input proj
    const bf16* __restrict__ gxb,      // [B][T][384] backward-dir input proj
    const float* __restrict__ whh_f, const float* __restrict__ whh_b,
    const float* __restrict__ bhh_f, const float* __restrict__ bhh_b,
    float* __restrict__ ys,            // [B][T][256], dir*128 col offset
    float* __restrict__ hfin)          // layer1: patient_emb f32 (or null)
{
  const int blk = blockIdx.x;
  const int dir = blk >> 7;
  const int b   = blk & 127;
  const int g   = threadIdx.x;       // 0..383: gate index
  const int p   = threadIdx.y;       // 0..1: d-half
  const float* whh = dir ? whh_b : whh_f;
  const float* bhh = dir ? bhh_b : bhh_f;
  const bf16* gx   = (dir ? gxb : gxf) + (size_t)b*TT*384;
  __shared__ __align__(16) float s_h[HH];
  __shared__ float s_gh  [3*HH];     // p=0 partial (incl. bhh)
  __shared__ float s_part[3*HH];     // p=1 partial
  __shared__ float s_gx  [3*HH];
  float4 w[HH/8];                    // 16 float4 = this thread's 64 weights
  #pragma unroll
  for (int d4 = 0; d4 < HH/8; ++d4)
    w[d4] = *(const float4*)&whh[(size_t)g*HH + p*64 + 4*d4];
  const float bh = p ? 0.f : bhh[g];
  float hreg = 0.f;
  if (p == 0 && g < HH) s_h[g] = 0.f;
  __syncthreads();
  for (int s = 0; s < TT; ++s) {
    const int t = dir ? (TT-1-s) : s;
    float gxv = 0.f;
    if (p == 0) gxv = b2f(gx[(size_t)t*384 + g]);
    float acc = bh;
    const float4* h4 = (const float4*)&s_h[p*64];
    #pragma unroll
    for (int d4 = 0; d4 < HH/8; ++d4) {
      const float4 hv = h4[d4];
      acc = fmaf(hv.x, w[d4].x, acc);
      acc = fmaf(hv.y, w[d4].y, acc);
      acc = fmaf(hv.z, w[d4].z, acc);
      acc = fmaf(hv.w, w[d4].w, acc);
    }
    if (p == 0) { s_gh[g] = acc; s_gx[g] = gxv; }
    else        { s_part[g] = acc; }
    __syncthreads();   // all dot-reads of s_h complete; partials visible
    if (p == 0 && g < HH) {
      const float r  = sigm_fast(s_gx[g]      + s_gh[g]      + s_part[g]);
      const float zg = sigm_fast(s_gx[HH+g]   + s_gh[HH+g]   + s_part[HH+g]);
      const float nn = tanh_fast(s_gx[2*HH+g] + r*(s_gh[2*HH+g] + s_part[2*HH+g]));
      hreg = (1.f - zg)*nn + zg*hreg;
      s_h[g] = hreg;
      ys[((size_t)b*TT + t)*256 + dir*HH + g] = hreg;
    }
    __syncthreads();   // new s_h visible before next step's dot
  }
  if (p == 0 && g < HH && hfin) hfin[(size_t)b*256 + dir*HH + g] = hreg;
}

// ---------------- heads ------------------------------------------------------
__global__ __launch_bounds__(64) void heads_k(
    const float* __restrict__ pemb,
    const float* __restrict__ mw1, const float* __restrict__ mb1,
    const float* __restrict__ mw2, const float* __restrict__ mb2,
    const float* __restrict__ cw1, const float* __restrict__ cb1,
    const float* __restrict__ cw2, const float* __restrict__ cb2,
    float* __restrict__ out)
{
  const int b = blockIdx.x, tid = threadIdx.x;
  __shared__ float sh[64];
  const float* pe = pemb + (size_t)b*256;
  float acc = mb1[tid];
  for (int d = 0; d < 256; ++d) acc = fmaf(pe[d], mw1[(size_t)tid*256 + d], acc);
  sh[tid] = fmaxf(acc, 0.f) * mw2[tid];
  __syncthreads();
  if (tid == 0) {
    float s = mb2[0];
    for (int i = 0; i < 64; ++i) s += sh[i];
    out[b]       = s;
    out[128 + b] = 1.f/(1.f + expf(-s));
  }
  __syncthreads();
  acc = cb1[tid];
  for (int d = 0; d < 256; ++d) acc = fmaf(pe[d], cw1[(size_t)tid*256 + d], acc);
  sh[tid] = fmaxf(acc, 0.f) * cw2[tid];
  __syncthreads();
  if (tid == 0) {
    float s = cb2[0];
    for (int i = 0; i < 64; ++i) s += sh[i];
    out[256 + b] = s;
  }
}

// ---------------- launch -----------------------------------------------------
extern "C" void kernel_launch(void* const* d_in, const int* in_sizes, int n_in,
                              void* d_out, int out_size, void* d_ws, size_t ws_size,
                              hipStream_t stream) {
  const float* X    = (const float*)d_in[0];
  const float* Mk   = (const float*)d_in[1];
  const float* Dl   = (const float*)d_in[2];
  const float* Tm   = (const float*)d_in[3];
  const float* Adj  = (const float*)d_in[4];
  const float* aw0  = (const float*)d_in[5];
  const float* ab0  = (const float*)d_in[6];
  const float* aWt  = (const float*)d_in[7];
  const float* aBt  = (const float*)d_in[8];
  const float* dw0  = (const float*)d_in[9];
  const float* db0  = (const float*)d_in[10];
  const float* dWt  = (const float*)d_in[11];
  const float* dBt  = (const float*)d_in[12];
  const float* gW0  = (const float*)d_in[13];
  const float* gas0 = (const float*)d_in[14];
  const float* gad0 = (const float*)d_in[15];
  const float* gW1  = (const float*)d_in[16];
  const float* gas1 = (const float*)d_in[17];
  const float* gad1 = (const float*)d_in[18];
  const float* g0f_wih = (const float*)d_in[19];
  const float* g0f_whh = (const float*)d_in[20];
  const float* g0f_bih = (const float*)d_in[21];
  const float* g0f_bhh = (const float*)d_in[22];
  const float* g0b_wih = (const float*)d_in[23];
  const float* g0b_whh = (const float*)d_in[24];
  const float* g0b_bih = (const float*)d_in[25];
  const float* g0b_bhh = (const float*)d_in[26];
  const float* g1f_wih = (const float*)d_in[27];
  const float* g1f_whh = (const float*)d_in[28];
  const float* g1f_bih = (const float*)d_in[29];
  const float* g1f_bhh = (const float*)d_in[30];
  const float* g1b_wih = (const float*)d_in[31];
  const float* g1b_whh = (const float*)d_in[32];
  const float* g1b_bih = (const float*)d_in[33];
  const float* g1b_bhh = (const float*)d_in[34];
  const float* mh_w1 = (const float*)d_in[35];
  const float* mh_b1 = (const float*)d_in[36];
  const float* mh_w2 = (const float*)d_in[37];
  const float* mh_b2 = (const float*)d_in[38];
  const float* ch_w1 = (const float*)d_in[39];
  const float* ch_b1 = (const float*)d_in[40];
  const float* ch_w2 = (const float*)d_in[41];
  const float* ch_b2 = (const float*)d_in[42];

  // workspace: gxA[12582912 bf16] | gxB[12582912 bf16] = 48 MiB
  bf16* gxA = (bf16*)d_ws;
  bf16* gxB = gxA + 12582912;

  float* out  = (float*)d_out;
  // out layout (fp32): m[128] | sig[128] | risk[128] | pemb[32768] | gru_out[B*T*256]
  float* pemb = out + 384;
  float* slot = out + 384 + 32768;     // gru_out slot, also hosts z and y

  // prep GAT weight + score-column tables (device globals; tiny)
  prep_w<<<72, 256, 0, stream>>>(gW0, gW1, gas0, gad0, gas1, gad1);

  gat_fused<<<dim3(BB*TT), dim3(256), 0, stream>>>(
      X, Mk, Dl, Tm, Adj, aw0, ab0, aWt, aBt, dw0, db0, dWt, dBt, slot);

  dim3 ggrid(32768/64, 384/64, 2);
  // layer-0 input projections (both dirs, z-split): A = z at slot cols
  // 128..255 (pitch 256), K=128
  gemm_xw_mfma<<<ggrid, 256, 0, stream>>>(slot + 128, 256,
      g0f_wih, g0f_bih, gxA, g0b_wih, g0b_bih, gxB, 128);
  // layer-0 recurrence: writes y = [yf|yb] into slot (dir1 overwrites dead z)
  gru_rec<<<256, dim3(384, 2), 0, stream>>>(gxA, gxB, g0f_whh, g0b_whh,
                                            g0f_bhh, g0b_bhh, slot, nullptr);
  // layer-1 input projections (both dirs): A = y at slot cols 0..255, K=256
  gemm_xw_mfma<<<ggrid, 256, 0, stream>>>(slot, 256,
      g1f_wih, g1f_bih, gxA, g1b_wih, g1b_bih, gxB, 256);
  // layer-1 recurrence: writes gru_out into slot (y dead), pemb fp32
  gru_rec<<<256, dim3(384, 2), 0, stream>>>(gxA, gxB, g1f_whh, g1b_whh,
                                            g1f_bhh, g1b_bhh, slot, pemb);

  heads_k<<<128, 64, 0, stream>>>(pemb, mh_w1, mh_b1, mh_w2, mh_b2,
                                  ch_w1, ch_b1, ch_w2, ch_b2, out);
}

// Round 16
// 1193.270 us; speedup vs baseline: 1.0390x; 1.0390x over previous
//
#include <hip/hip_runtime.h>
#include <hip/hip_bf16.h>
#include <math.h>

// Problem constants
#define NFE 17      // graph nodes (features)
#define T2V 16      // time2vec dim
#define D0C 34      // 2 + 2*T2V
#define BB 128      // batch
#define TT 256      // seq len
#define HH 128      // GRU hidden
#define PSTR 132    // padded row stride; 132*4B=528B -> every row 16B aligned
#define ASTR 136    // bf16 split-buffer row stride; 136*2B=272B -> 16B aligned
#define KSTR 40     // P^T k-stride: 80B rows, 16B aligned
#define ESTR 40     // E row stride; 80B rows, 16B aligned
#define EHSTR 680   // E head stride = 17*ESTR

typedef __hip_bfloat16 bf16;
__device__ __forceinline__ float b2f(bf16 x) { return __bfloat162float(x); }

// MFMA fragment types (gfx950 16x16x32 bf16: 8 bf16 in / 4 f32 acc per lane)
typedef __attribute__((ext_vector_type(8))) __bf16 bfrag;
typedef __attribute__((ext_vector_type(4))) float  ffrag;
typedef __attribute__((ext_vector_type(4))) __bf16 bf4;

// fast transcendentals (native v_exp_f32/v_sin_f32; ~2ulp)
__device__ __forceinline__ float elu_fast(float v)  { return v > 0.f ? v : __expf(v) - 1.f; }
__device__ __forceinline__ float sigm_fast(float x) { return __fdividef(1.f, 1.f + __expf(-x)); }
__device__ __forceinline__ float tanh_fast(float x) {
  return __fdividef(2.f, 1.f + __expf(-2.f*x)) - 1.f;
}

// ---------------- GAT weight fragment tables (prep once per launch) ----------
__device__ __bf16 g_W0h[8192],  g_W0l[8192];    // KSTEPS=2 (K 34 -> pad 64)
__device__ __bf16 g_W1h[16384], g_W1l[16384];   // KSTEPS=4 (K=128)

__global__ __launch_bounds__(256) void prep_w(const float* __restrict__ W0,
                                              const float* __restrict__ W1) {
  const int tid = blockIdx.x*256 + threadIdx.x;
  if (tid < 16384) {
    const int j = tid & 7, lane = (tid >> 3) & 63, ks = (tid >> 9) & 3, nt = tid >> 11;
    const int n = nt*16 + (lane & 15), k = ks*32 + (lane >> 4)*8 + j;
    const float v = W1[k*128 + n];
    const __bf16 hi = (__bf16)v;
    g_W1h[tid] = hi;
    g_W1l[tid] = (__bf16)(v - (float)hi);
  }
  if (tid < 8192) {
    const int j = tid & 7, lane = (tid >> 3) & 63, ks = (tid >> 9) & 1, nt = tid >> 10;
    const int n = nt*16 + (lane & 15), k = ks*32 + (lane >> 4)*8 + j;
    const float v = (k < D0C) ? W0[k*128 + n] : 0.f;
    const __bf16 hi = (__bf16)v;
    g_W0h[tid] = hi;
    g_W0l[tid] = (__bf16)(v - (float)hi);
  }
}

// ---------------- GAT building blocks ----------------------------------------
// FINAL (R12/R14-verified best, 1193.8/1196.1us): R10 gat_fused (f32 s_p
// scores — R11 split-P scores regressed; R15 MFMA-scores regressed: the
// wave-0-only score tile serialized work onto the longest wave's critical
// path while the deleted scores dot was parallel across all 4 waves) +
// z-merged W-in-LDS GEMM (R13 table variant neutral) + R23 chain-split
// gru_rec. Session: 1643 -> 1194 us.
template<int KSTEPS>
__device__ __forceinline__ void gat_proj_mfma(const __bf16* s_ah, const __bf16* s_al,
                                              const __bf16* __restrict__ Wth,
                                              const __bf16* __restrict__ Wtl,
                                              float* s_p, __bf16* s_pth, __bf16* s_ptl,
                                              int tid)
{
  const int lane = tid & 63, wv = tid >> 6;
  const int mn = lane & 15, q = lane >> 4;
  ffrag acc[2][2] = {};
  #pragma unroll
  for (int ks = 0; ks < KSTEPS; ++ks) {
    const bfrag ah0 = *(const bfrag*)&s_ah[(     mn)*ASTR + ks*32 + q*8];
    const bfrag al0 = *(const bfrag*)&s_al[(     mn)*ASTR + ks*32 + q*8];
    const bfrag ah1 = *(const bfrag*)&s_ah[(16 + mn)*ASTR + ks*32 + q*8]; // rows 17+ garbage, discarded
    const bfrag al1 = *(const bfrag*)&s_al[(16 + mn)*ASTR + ks*32 + q*8];
    #pragma unroll
    for (int nt = 0; nt < 2; ++nt) {
      const int fi = (((wv*2 + nt)*KSTEPS + ks)*64 + lane)*8;
      const bfrag bh = *(const bfrag*)&Wth[fi];
      const bfrag bl = *(const bfrag*)&Wtl[fi];
      acc[0][nt] = __builtin_amdgcn_mfma_f32_16x16x32_bf16(al0, bh, acc[0][nt], 0,0,0);
      acc[0][nt] = __builtin_amdgcn_mfma_f32_16x16x32_bf16(ah0, bl, acc[0][nt], 0,0,0);
      acc[0][nt] = __builtin_amdgcn_mfma_f32_16x16x32_bf16(ah0, bh, acc[0][nt], 0,0,0);
      acc[1][nt] = __builtin_amdgcn_mfma_f32_16x16x32_bf16(al1, bh, acc[1][nt], 0,0,0);
      acc[1][nt] = __builtin_amdgcn_mfma_f32_16x16x32_bf16(ah1, bl, acc[1][nt], 0,0,0);
      acc[1][nt] = __builtin_amdgcn_mfma_f32_16x16x32_bf16(ah1, bh, acc[1][nt], 0,0,0);
    }
  }
  // C/D: col = lane&15 (+16*nt +32*wv), row = q*4+i (tile0) / 16 (tile1,q0).
  const int n0 = wv*32;
  #pragma unroll
  for (int nt = 0; nt < 2; ++nt) {
    const int col = n0 + nt*16 + mn;
    __bf16 hbuf[4], lbuf[4];
    #pragma unroll
    for (int i = 0; i < 4; ++i) {
      const float v = acc[0][nt][i];
      s_p[(q*4 + i)*PSTR + col] = v;
      const __bf16 hi = (__bf16)v;
      hbuf[i] = hi;
      lbuf[i] = (__bf16)(v - (float)hi);
    }
    *(bf4*)&s_pth[col*KSTR + q*4] = *(bf4*)hbuf;
    *(bf4*)&s_ptl[col*KSTR + q*4] = *(bf4*)lbuf;
    if (q == 0) {
      const float v = acc[1][nt][0];
      s_p[16*PSTR + col] = v;
      const __bf16 hi = (__bf16)v;
      s_pth[col*KSTR + 16] = hi;
      s_ptl[col*KSTR + 16] = (__bf16)(v - (float)hi);
    }
  }
}

// scores + softmax + E-write, one wave per head.
// lanes 0..16: es rows; lanes 32..48: ed rows; shfl-broadcast; softmax once
// per row by lanes 0..16; E written hi/lo with zero j-pads (17..31).
__device__ __forceinline__ void gat_scoresm(const float* s_p,
                                            const float* __restrict__ asrc,
                                            const float* __restrict__ adst,
                                            const float* s_adj,
                                            __bf16* s_Eh, __bf16* s_El, int tid) {
  const int lane = tid & 63, h = tid >> 6;   // wave h = head h
  const int f = lane & 31;
  float sc = 0.f;
  if (f < NFE) {
    const float* av = (lane < 32) ? asrc : adst;
    #pragma unroll
    for (int o = 0; o < 32; o += 4) {
      const float4 p4 = *(const float4*)&s_p[f*PSTR + h*32 + o];
      const float4 a4 = *(const float4*)&av[h*32 + o];
      sc = fmaf(p4.x, a4.x, sc); sc = fmaf(p4.y, a4.y, sc);
      sc = fmaf(p4.z, a4.z, sc); sc = fmaf(p4.w, a4.w, sc);
    }
  }
  float ed[NFE];
  #pragma unroll
  for (int j = 0; j < NFE; ++j) ed[j] = __shfl(sc, 32 + j);
  if (lane < NFE) {
    const int i = lane;
    const float esv = sc;
    float row[NFE]; float mx = -1e30f;
    #pragma unroll
    for (int j = 0; j < NFE; ++j) {
      float v = -1.0e9f;
      if (s_adj[i*NFE + j] > 0.f) {
        const float e = esv + ed[j];
        v = (e > 0.f) ? e : 0.2f*e;    // leaky_relu 0.2
      }
      row[j] = v; mx = fmaxf(mx, v);
    }
    float sum = 0.f;
    #pragma unroll
    for (int j = 0; j < NFE; ++j) { row[j] = __expf(row[j] - mx); sum += row[j]; }
    const float inv = __fdividef(1.f, sum);
    __bf16 hrow[32], lrow[32];
    #pragma unroll
    for (int j = 0; j < 32; ++j) {
      const float v = (j < NFE) ? row[j]*inv : 0.f;
      const __bf16 hi = (__bf16)v;
      hrow[j] = hi;
      lrow[j] = (__bf16)(v - (float)hi);
    }
    #pragma unroll
    for (int w = 0; w < 4; ++w) {
      *(bfrag*)&s_Eh[h*EHSTR + i*ESTR + w*8] = *(bfrag*)&hrow[w*8];
      *(bfrag*)&s_El[h*EHSTR + i*ESTR + w*8] = *(bfrag*)&lrow[w*8];
    }
  }
}

// out-stage core: b128-load E fragments and do O = E.P per head
__device__ __forceinline__ void gat_out_core(const __bf16* s_Eh, const __bf16* s_El,
                                             const __bf16* s_pth, const __bf16* s_ptl,
                                             int wv, int mn, int q, ffrag acc[2][2]) {
  const bfrag eh0 = *(const bfrag*)&s_Eh[wv*EHSTR + mn*ESTR + q*8];
  const bfrag el0 = *(const bfrag*)&s_El[wv*EHSTR + mn*ESTR + q*8];
  const bfrag eh1 = *(const bfrag*)&s_Eh[wv*EHSTR + (16+mn)*ESTR + q*8]; // rows 17+ garbage, discarded
  const bfrag el1 = *(const bfrag*)&s_El[wv*EHSTR + (16+mn)*ESTR + q*8];
  #pragma unroll
  for (int nt = 0; nt < 2; ++nt) {
    const int nrow = wv*32 + nt*16 + mn;
    const bfrag ph = *(const bfrag*)&s_pth[nrow*KSTR + q*8];
    const bfrag pl = *(const bfrag*)&s_ptl[nrow*KSTR + q*8];
    acc[0][nt] = __builtin_amdgcn_mfma_f32_16x16x32_bf16(el0, ph, acc[0][nt], 0,0,0);
    acc[0][nt] = __builtin_amdgcn_mfma_f32_16x16x32_bf16(eh0, pl, acc[0][nt], 0,0,0);
    acc[0][nt] = __builtin_amdgcn_mfma_f32_16x16x32_bf16(eh0, ph, acc[0][nt], 0,0,0);
    acc[1][nt] = __builtin_amdgcn_mfma_f32_16x16x32_bf16(el1, ph, acc[1][nt], 0,0,0);
    acc[1][nt] = __builtin_amdgcn_mfma_f32_16x16x32_bf16(eh1, pl, acc[1][nt], 0,0,0);
    acc[1][nt] = __builtin_amdgcn_mfma_f32_16x16x32_bf16(eh1, ph, acc[1][nt], 0,0,0);
  }
}

// layer-0 out: h = elu(E.P) -> split bf16 into s_ah/s_al (proj1 input)
__device__ __forceinline__ void gat_out0(const __bf16* s_Eh, const __bf16* s_El,
                                         const __bf16* s_pth, const __bf16* s_ptl,
                                         __bf16* s_ah, __bf16* s_al, int tid) {
  const int lane = tid & 63, wv = tid >> 6;   // wv = head
  const int mn = lane & 15, q = lane >> 4;
  ffrag acc[2][2] = {};
  gat_out_core(s_Eh, s_El, s_pth, s_ptl, wv, mn, q, acc);
  #pragma unroll
  for (int nt = 0; nt < 2; ++nt) {
    const int c = wv*32 + nt*16 + mn;
    #pragma unroll
    for (int i = 0; i < 4; ++i) {
      const float v = elu_fast(acc[0][nt][i]);
      const __bf16 hi = (__bf16)v;
      s_ah[(q*4+i)*ASTR + c] = hi;
      s_al[(q*4+i)*ASTR + c] = (__bf16)(v - (float)hi);
    }
    if (q == 0) {
      const float v = elu_fast(acc[1][nt][0]);
      const __bf16 hi = (__bf16)v;
      s_ah[16*ASTR + c] = hi;
      s_al[16*ASTR + c] = (__bf16)(v - (float)hi);
    }
  }
}

// layer-1 out: + residual + elu + column-mean (shfl-reduce) -> global z
__device__ __forceinline__ void gat_out1(const __bf16* s_Eh, const __bf16* s_El,
                                         const __bf16* s_pth, const __bf16* s_ptl,
                                         const __bf16* s_ah, const __bf16* s_al,
                                         float* __restrict__ zrow, int tid) {
  const int lane = tid & 63, wv = tid >> 6;   // wv = head
  const int mn = lane & 15, q = lane >> 4;
  ffrag acc[2][2] = {};
  gat_out_core(s_Eh, s_El, s_pth, s_ptl, wv, mn, q, acc);
  #pragma unroll
  for (int nt = 0; nt < 2; ++nt) {
    const int c = wv*32 + nt*16 + mn;
    float sum = 0.f;
    #pragma unroll
    for (int i = 0; i < 4; ++i) {
      const int r = q*4 + i;
      const float res = (float)s_ah[r*ASTR + c] + (float)s_al[r*ASTR + c];
      sum += elu_fast(acc[0][nt][i] + res);
    }
    sum += __shfl_xor(sum, 16);
    sum += __shfl_xor(sum, 32);
    if (q == 0) {
      const float res = (float)s_ah[16*ASTR + c] + (float)s_al[16*ASTR + c];
      sum += elu_fast(acc[1][nt][0] + res);
      zrow[c] = sum * (1.0f/17.0f);
    }
  }
}

// --------------- fused featurize + GAT0 + GAT1 + node-mean -------------------
// Flat LDS carve (byte offsets; all 16B aligned):
//  s_ah   @0      4624   } tile-1 frag reads intentionally run past into
//  s_al   @4624   4624   } following regions (finite/discarded-rows only)
//  s_p    @9248   8976   (f32, scores input)
//  s_Eh   @18224  5440   ([4][17][ESTR=40] bf16; j-pads zero)
//  s_El   @23664  5440
//  s_pth  @29104  10240  (P^T split hi, [n=128][KSTR=40]; k 17..39 stay 0)
//  s_ptl  @39344  10240
//  s_t    @49584  64
//  s_adj  @49648  1156
//  total  50804 -> 50816  => 3 blocks/CU
__global__ __launch_bounds__(256) void gat_fused(
    const float* __restrict__ X,  const float* __restrict__ Mk,
    const float* __restrict__ Dl, const float* __restrict__ Tm,
    const float* __restrict__ Adj,
    const float* __restrict__ aw0, const float* __restrict__ ab0,
    const float* __restrict__ aW,  const float* __restrict__ aB,
    const float* __restrict__ dw0, const float* __restrict__ db0,
    const float* __restrict__ dW,  const float* __restrict__ dB,
    const float* __restrict__ as0, const float* __restrict__ ad0,
    const float* __restrict__ as1, const float* __restrict__ ad1,
    float* __restrict__ zslot)         // [B*T][256], z goes in cols 128..255
{
  __shared__ __align__(16) unsigned char smem[50816];
  __bf16* s_ah  = (__bf16*)(smem);
  __bf16* s_al  = (__bf16*)(smem + 4624);
  float*  s_p   = (float*)(smem + 9248);
  __bf16* s_Eh  = (__bf16*)(smem + 18224);
  __bf16* s_El  = (__bf16*)(smem + 23664);
  __bf16* s_pth = (__bf16*)(smem + 29104);
  __bf16* s_ptl = (__bf16*)(smem + 39344);
  float*  s_t   = (float*)(smem + 49584);
  float*  s_adj = (float*)(smem + 49648);
  const int n = blockIdx.x;            // n = b*T + t  (matches times layout)
  const int tid = threadIdx.x;

  // zero P^T split buffers once: k-pad 17..39 MUST be 0 (proj only ever
  // writes k 0..16, so the pad stays 0 across both layers)
  {
    const float4 z4 = {0.f, 0.f, 0.f, 0.f};
    float4* zp = (float4*)(smem + 29104);
    for (int i = tid; i < 1280; i += 256) zp[i] = z4;
  }
  const float tv = Tm[n];
  if (tid < T2V) {
    s_t[tid] = (tid == 0) ? fmaf(tv, aw0[0], ab0[0])
                          : __sinf(fmaf(tv, aW[tid-1], aB[tid-1]));
  }
  for (int idx = tid; idx < NFE*NFE; idx += 256) s_adj[idx] = Adj[idx];
  __syncthreads();
  // node features: [X, mask, t_emb(16), d_emb(16), 0-pad to 64] -> split bf16.
  // K-pad cols of real rows MUST be zero (NaN*0=NaN would hit real rows).
  for (int idx = tid; idx < NFE*64; idx += 256) {
    const int f = idx >> 6, c = idx & 63;
    float v = 0.f;
    if (c == 0)            v = X [(size_t)n*NFE + f];
    else if (c == 1)       v = Mk[(size_t)n*NFE + f];
    else if (c < 2 + T2V)  v = s_t[c-2];
    else if (c < D0C) {
      const float dd = Dl[(size_t)n*NFE + f];
      const int j = c - (2 + T2V);
      v = (j == 0) ? fmaf(dd, dw0[0], db0[0])
                   : __sinf(fmaf(dd, dW[j-1], dB[j-1]));
    }
    const __bf16 hi = (__bf16)v;
    s_ah[f*ASTR + c] = hi;
    s_al[f*ASTR + c] = (__bf16)(v - (float)hi);
  }
  __syncthreads();
  // GAT layer 0 (no residual)
  gat_proj_mfma<2>(s_ah, s_al, g_W0h, g_W0l, s_p, s_pth, s_ptl, tid); __syncthreads();
  gat_scoresm(s_p, as0, ad0, s_adj, s_Eh, s_El, tid);                 __syncthreads();
  gat_out0(s_Eh, s_El, s_pth, s_ptl, s_ah, s_al, tid);                __syncthreads();
  // GAT layer 1 (residual) -> out + fused node-mean -> global
  gat_proj_mfma<4>(s_ah, s_al, g_W1h, g_W1l, s_p, s_pth, s_ptl, tid); __syncthreads();
  gat_scoresm(s_p, as1, ad1, s_adj, s_Eh, s_El, tid);                 __syncthreads();
  gat_out1(s_Eh, s_El, s_pth, s_ptl, s_ah, s_al,
           zslot + (size_t)n*256 + 128, tid);
}

// ------- MFMA GEMM (full split-precision): C = A(f32)*W(f32)^T + bias
// A = Ahi+Alo, W = Whi+Wlo (bf16 pairs). C ≈ Alo*Whi + Ahi*Wlo + Ahi*Whi
// (Alo*Wlo ~2^-18 dropped) -> ~fp32 accuracy.
// fwd/bwd directions merged into one dispatch via blockIdx.z (R10-proven).
// W staged in LDS (shared by all 4 waves) — R13's per-wave table variant
// measured neutral-to-worse.
// Fragment layouts (HW-verified, guide m89/m91):
//   A-frag: A[m=lane&15][k=quad*8+j]   B-frag: W[n=lane&15][k=quad*8+j]
//   C/D   : col(n)=lane&15, row(m)=quad*4+reg
__global__ __launch_bounds__(256) void gemm_xw_mfma(
    const float* __restrict__ A, int lda,
    const float* __restrict__ Wf, const float* __restrict__ biasf,
    bf16* __restrict__ Cf,
    const float* __restrict__ Wb, const float* __restrict__ biasb,
    bf16* __restrict__ Cb, int K)
{
  const float* W    = blockIdx.z ? Wb : Wf;
  const float* bias = blockIdx.z ? biasb : biasf;
  bf16*        C    = blockIdx.z ? Cb : Cf;
  __shared__ __bf16 Ah[64][40];   // pad 32->40: row = 80 B (16B-aligned)
  __shared__ __bf16 Al[64][40];
  __shared__ __bf16 Wh[64][40];
  __shared__ __bf16 Wl[64][40];
  const int tid = threadIdx.x;
  const int bm0 = blockIdx.x * 64;
  const int bn0 = blockIdx.y * 64;
  const int lane = tid & 63, wv = tid >> 6;
  const int mn = lane & 15, q = lane >> 4;
  const int sr = tid >> 2, sk = (tid & 3) * 8;   // staging: row, k-offset
  ffrag acc[4] = {};
  for (int kk = 0; kk < K; kk += 32) {
    // stage A and W chunks, each split hi/lo; coalesced float4 reads
    {
      float av[8];
      *(float4*)&av[0] = *(const float4*)&A[(size_t)(bm0 + sr)*lda + kk + sk];
      *(float4*)&av[4] = *(const float4*)&A[(size_t)(bm0 + sr)*lda + kk + sk + 4];
      __bf16 th[8], tl[8];
      #pragma unroll
      for (int i = 0; i < 8; ++i) {
        const __bf16 hi = (__bf16)av[i];
        th[i] = hi;
        tl[i] = (__bf16)(av[i] - (float)hi);
      }
      *(bfrag*)&Ah[sr][sk] = *(bfrag*)th;
      *(bfrag*)&Al[sr][sk] = *(bfrag*)tl;
      float wv8[8];
      *(float4*)&wv8[0] = *(const float4*)&W[(size_t)(bn0 + sr)*K + kk + sk];
      *(float4*)&wv8[4] = *(const float4*)&W[(size_t)(bn0 + sr)*K + kk + sk + 4];
      __bf16 wh8[8], wl8[8];
      #pragma unroll
      for (int i = 0; i < 8; ++i) {
        const __bf16 hi = (__bf16)wv8[i];
        wh8[i] = hi;
        wl8[i] = (__bf16)(wv8[i] - (float)hi);
      }
      *(bfrag*)&Wh[sr][sk] = *(bfrag*)wh8;
      *(bfrag*)&Wl[sr][sk] = *(bfrag*)wl8;
    }
    __syncthreads();
    const bfrag afh = *(const bfrag*)&Ah[16*wv + mn][q*8];
    const bfrag afl = *(const bfrag*)&Al[16*wv + mn][q*8];
    #pragma unroll
    for (int t = 0; t < 4; ++t) {
      const bfrag bwh = *(const bfrag*)&Wh[16*t + mn][q*8];
      const bfrag bwl = *(const bfrag*)&Wl[16*t + mn][q*8];
      acc[t] = __builtin_amdgcn_mfma_f32_16x16x32_bf16(afl, bwh, acc[t], 0, 0, 0);
      acc[t] = __builtin_amdgcn_mfma_f32_16x16x32_bf16(afh, bwl, acc[t], 0, 0, 0);
      acc[t] = __builtin_amdgcn_mfma_f32_16x16x32_bf16(afh, bwh, acc[t], 0, 0, 0);
    }
    __syncthreads();
  }
  // epilogue: C[m][n] = acc + bias
  #pragma unroll
  for (int t = 0; t < 4; ++t) {
    const int col = bn0 + 16*t + mn;
    const float bv = bias[col];
    #pragma unroll
    for (int i = 0; i < 4; ++i) {
      const int row = bm0 + 16*wv + q*4 + i;
      C[(size_t)row*384 + col] = __float2bfloat16(acc[t][i] + bv);
    }
  }
}

// ---------------- GRU recurrence: one block per (dir, batch-row) -------------
// R23-proven: dependent-chain split. Thread (g,p) computes the half-dot over
// d in [p*64, p*64+64) (64-deep chain vs 128; w-regs halve -> no spill).
// p=1 stores its partial; gate threads add it — no extra barrier.
__global__ __launch_bounds__(768, 1) void gru_rec(
    const bf16* __restrict__ gxf,      // [B][T][384] forward-dir input proj
    const bf16* __restrict__ gxb,      // [B][T][384] backward-dir input proj
    const float* __restrict__ whh_f, const float* __restrict__ whh_b,
    const float* __restrict__ bhh_f, const float* __restrict__ bhh_b,
    float* __restrict__ ys,            // [B][T][256], dir*128 col offset
    float* __restrict__ hfin)          // layer1: patient_emb f32 (or null)
{
  const int blk = blockIdx.x;
  const int dir = blk >> 7;
  const int b   = blk & 127;
  const int g   = threadIdx.x;       // 0..383: gate index
  const int p   = threadIdx.y;       // 0..1: d-half
  const float* whh = dir ? whh_b : whh_f;
  const float* bhh = dir ? bhh_b : bhh_f;
  const bf16* gx   = (dir ? gxb : gxf) + (size_t)b*TT*384;
  __shared__ __align__(16) float s_h[HH];
  __shared__ float s_gh  [3*HH];     // p=0 partial (incl. bhh)
  __shared__ float s_part[3*HH];     // p=1 partial
  __shared__ float s_gx  [3*HH];
  float4 w[HH/8];                    // 16 float4 = this thread's 64 weights
  #pragma unroll
  for (int d4 = 0; d4 < HH/8; ++d4)
    w[d4] = *(const float4*)&whh[(size_t)g*HH + p*64 + 4*d4];
  const float bh = p ? 0.f : bhh[g];
  float hreg = 0.f;
  if (p == 0 && g < HH) s_h[g] = 0.f;
  __syncthreads();
  for (int s = 0; s < TT; ++s) {
    const int t = dir ? (TT-1-s) : s;
    float gxv = 0.f;
    if (p == 0) gxv = b2f(gx[(size_t)t*384 + g]);
    float acc = bh;
    const float4* h4 = (const float4*)&s_h[p*64];
    #pragma unroll
    for (int d4 = 0; d4 < HH/8; ++d4) {
      const float4 hv = h4[d4];
      acc = fmaf(hv.x, w[d4].x, acc);
      acc = fmaf(hv.y, w[d4].y, acc);
      acc = fmaf(hv.z, w[d4].z, acc);
      acc = fmaf(hv.w, w[d4].w, acc);
    }
    if (p == 0) { s_gh[g] = acc; s_gx[g] = gxv; }
    else        { s_part[g] = acc; }
    __syncthreads();   // all dot-reads of s_h complete; partials visible
    if (p == 0 && g < HH) {
      const float r  = sigm_fast(s_gx[g]      + s_gh[g]      + s_part[g]);
      const float zg = sigm_fast(s_gx[HH+g]   + s_gh[HH+g]   + s_part[HH+g]);
      const float nn = tanh_fast(s_gx[2*HH+g] + r*(s_gh[2*HH+g] + s_part[2*HH+g]));
      hreg = (1.f - zg)*nn + zg*hreg;
      s_h[g] = hreg;
      ys[((size_t)b*TT + t)*256 + dir*HH + g] = hreg;
    }
    __syncthreads();   // new s_h visible before next step's dot
  }
  if (p == 0 && g < HH && hfin) hfin[(size_t)b*256 + dir*HH + g] = hreg;
}

// ---------------- heads ------------------------------------------------------
__global__ __launch_bounds__(64) void heads_k(
    const float* __restrict__ pemb,
    const float* __restrict__ mw1, const float* __restrict__ mb1,
    const float* __restrict__ mw2, const float* __restrict__ mb2,
    const float* __restrict__ cw1, const float* __restrict__ cb1,
    const float* __restrict__ cw2, const float* __restrict__ cb2,
    float* __restrict__ out)
{
  const int b = blockIdx.x, tid = threadIdx.x;
  __shared__ float sh[64];
  const float* pe = pemb + (size_t)b*256;
  float acc = mb1[tid];
  for (int d = 0; d < 256; ++d) acc = fmaf(pe[d], mw1[(size_t)tid*256 + d], acc);
  sh[tid] = fmaxf(acc, 0.f) * mw2[tid];
  __syncthreads();
  if (tid == 0) {
    float s = mb2[0];
    for (int i = 0; i < 64; ++i) s += sh[i];
    out[b]       = s;
    out[128 + b] = 1.f/(1.f + expf(-s));
  }
  __syncthreads();
  acc = cb1[tid];
  for (int d = 0; d < 256; ++d) acc = fmaf(pe[d], cw1[(size_t)tid*256 + d], acc);
  sh[tid] = fmaxf(acc, 0.f) * cw2[tid];
  __syncthreads();
  if (tid == 0) {
    float s = cb2[0];
    for (int i = 0; i < 64; ++i) s += sh[i];
    out[256 + b] = s;
  }
}

// ---------------- launch -----------------------------------------------------
extern "C" void kernel_launch(void* const* d_in, const int* in_sizes, int n_in,
                              void* d_out, int out_size, void* d_ws, size_t ws_size,
                              hipStream_t stream) {
  const float* X    = (const float*)d_in[0];
  const float* Mk   = (const float*)d_in[1];
  const float* Dl   = (const float*)d_in[2];
  const float* Tm   = (const float*)d_in[3];
  const float* Adj  = (const float*)d_in[4];
  const float* aw0  = (const float*)d_in[5];
  const float* ab0  = (const float*)d_in[6];
  const float* aWt  = (const float*)d_in[7];
  const float* aBt  = (const float*)d_in[8];
  const float* dw0  = (const float*)d_in[9];
  const float* db0  = (const float*)d_in[10];
  const float* dWt  = (const float*)d_in[11];
  const float* dBt  = (const float*)d_in[12];
  const float* gW0  = (const float*)d_in[13];
  const float* gas0 = (const float*)d_in[14];
  const float* gad0 = (const float*)d_in[15];
  const float* gW1  = (const float*)d_in[16];
  const float* gas1 = (const float*)d_in[17];
  const float* gad1 = (const float*)d_in[18];
  const float* g0f_wih = (const float*)d_in[19];
  const float* g0f_whh = (const float*)d_in[20];
  const float* g0f_bih = (const float*)d_in[21];
  const float* g0f_bhh = (const float*)d_in[22];
  const float* g0b_wih = (const float*)d_in[23];
  const float* g0b_whh = (const float*)d_in[24];
  const float* g0b_bih = (const float*)d_in[25];
  const float* g0b_bhh = (const float*)d_in[26];
  const float* g1f_wih = (const float*)d_in[27];
  const float* g1f_whh = (const float*)d_in[28];
  const float* g1f_bih = (const float*)d_in[29];
  const float* g1f_bhh = (const float*)d_in[30];
  const float* g1b_wih = (const float*)d_in[31];
  const float* g1b_whh = (const float*)d_in[32];
  const float* g1b_bih = (const float*)d_in[33];
  const float* g1b_bhh = (const float*)d_in[34];
  const float* mh_w1 = (const float*)d_in[35];
  const float* mh_b1 = (const float*)d_in[36];
  const float* mh_w2 = (const float*)d_in[37];
  const float* mh_b2 = (const float*)d_in[38];
  const float* ch_w1 = (const float*)d_in[39];
  const float* ch_b1 = (const float*)d_in[40];
  const float* ch_w2 = (const float*)d_in[41];
  const float* ch_b2 = (const float*)d_in[42];

  // workspace: gxA[12582912 bf16] | gxB[12582912 bf16] = 48 MiB
  bf16* gxA = (bf16*)d_ws;
  bf16* gxB = gxA + 12582912;

  float* out  = (float*)d_out;
  // out layout (fp32): m[128] | sig[128] | risk[128] | pemb[32768] | gru_out[B*T*256]
  float* pemb = out + 384;
  float* slot = out + 384 + 32768;     // gru_out slot, also hosts z and y

  // prep GAT weight fragment tables (device globals; tiny)
  prep_w<<<64, 256, 0, stream>>>(gW0, gW1);

  gat_fused<<<dim3(BB*TT), dim3(256), 0, stream>>>(
      X, Mk, Dl, Tm, Adj, aw0, ab0, aWt, aBt, dw0, db0, dWt, dBt,
      gas0, gad0, gas1, gad1, slot);

  dim3 ggrid(32768/64, 384/64, 2);
  // layer-0 input projections (both dirs, z-split): A = z at slot cols
  // 128..255 (pitch 256), K=128
  gemm_xw_mfma<<<ggrid, 256, 0, stream>>>(slot + 128, 256,
      g0f_wih, g0f_bih, gxA, g0b_wih, g0b_bih, gxB, 128);
  // layer-0 recurrence: writes y = [yf|yb] into slot (dir1 overwrites dead z)
  gru_rec<<<256, dim3(384, 2), 0, stream>>>(gxA, gxB, g0f_whh, g0b_whh,
                                            g0f_bhh, g0b_bhh, slot, nullptr);
  // layer-1 input projections (both dirs): A = y at slot cols 0..255, K=256
  gemm_xw_mfma<<<ggrid, 256, 0, stream>>>(slot, 256,
      g1f_wih, g1f_bih, gxA, g1b_wih, g1b_bih, gxB, 256);
  // layer-1 recurrence: writes gru_out into slot (y dead), pemb fp32
  gru_rec<<<256, dim3(384, 2), 0, stream>>>(gxA, gxB, g1f_whh, g1b_whh,
                                            g1f_bhh, g1b_bhh, slot, pemb);

  heads_k<<<128, 64, 0, stream>>>(pemb, mh_w1, mh_b1, mh_w2, mh_b2,
                                  ch_w1, ch_b1, ch_w2, ch_b2, out);
}